// Round 4
// baseline (4820.348 us; speedup 1.0000x reference)
//
#include <hip/hip_runtime.h>
#include <hip/hip_bf16.h>
#include <cstdint>

#define LEAKV 0.2f
static const int Bb = 4, Nn = 4096, Mm = 16384, Kk = 20;

__device__ __forceinline__ float lrelu_f(float v){ return v > 0.f ? v : LEAKV*v; }

// ---------- dtype detector: read as bf16, count wild values ----------
__global__ void detect_kernel(const void* __restrict__ xyz, int n, int* __restrict__ flag){
  __shared__ int cnt;
  if (threadIdx.x == 0) cnt = 0;
  __syncthreads();
  const __hip_bfloat16* p = (const __hip_bfloat16*)xyz;
  int local = 0;
  for (int i = threadIdx.x; i < n; i += 256){
    float v = __bfloat162float(p[i]);
    if (!(fabsf(v) < 1000.f)) local++;   // catches NaN/Inf/huge
  }
  atomicAdd(&cnt, local);
  __syncthreads();
  if (threadIdx.x == 0) *flag = (cnt < n/16) ? 1 : 0;   // 1 = bf16, 0 = fp32
}

// ---------- flag-gated input load -> fp32 ----------
__global__ void load_input_kernel(const void* __restrict__ src, const int* __restrict__ flag,
                                  float* __restrict__ out, int n){
  int t = blockIdx.x*256 + threadIdx.x;
  if (t >= n) return;
  if (*flag) out[t] = __bfloat162float(((const __hip_bfloat16*)src)[t]);
  else       out[t] = ((const float*)src)[t];
}

// ---------- flag-gated output store ----------
__global__ void store_out_kernel(const float* __restrict__ src, const int* __restrict__ flag,
                                 void* __restrict__ dst, int n){
  int t = blockIdx.x*256 + threadIdx.x;
  if (t >= n) return;
  float v = src[t];
  if (*flag) ((__hip_bfloat16*)dst)[t] = __float2bfloat16(v);
  else       ((float*)dst)[t] = v;
}

// ---------- squared norms ----------
__global__ void norms_kernel(const float* __restrict__ x, int ld, int C, int total, float* __restrict__ out){
  int t = blockIdx.x*256 + threadIdx.x;
  if (t >= total) return;
  const float* r = x + (size_t)t*ld;
  float s = 0.f;
  for (int c = 0; c < C; ++c){ float v = r[c]; s += v*v; }
  out[t] = s;
}

// ---------- distance strip GEMM: D[lq, j] = n2[j] - 2 * <x_q, x_j>  (one batch, 2048-query strip) ----------
__global__ __launch_bounds__(256) void dist_kernel(
    const float* __restrict__ x, int ld, int C, const float* __restrict__ n2,
    int bN, int q0, float* __restrict__ D)
{
  const int tid = threadIdx.x;
  const int tx = tid & 15, ty = tid >> 4;
  const int m0 = q0 + blockIdx.y * 64;   // query within batch
  const int j0 = blockIdx.x * 64;        // candidate within batch
  __shared__ __align__(16) float As[16*68];
  __shared__ __align__(16) float Ws[16*68];
  float acc[4][4] = {};
  for (int k0 = 0; k0 < C; k0 += 16){
    __syncthreads();
    #pragma unroll
    for (int r = 0; r < 4; ++r){
      int e = tid + r*256;
      int k = e & 15, mi = e >> 4;
      int kk = k0 + k;
      float av = 0.f, wv = 0.f;
      if (kk < C){
        av = x[(size_t)(bN + m0 + mi)*ld + kk];
        wv = x[(size_t)(bN + j0 + mi)*ld + kk];
      }
      As[k*68 + mi] = av;
      Ws[k*68 + mi] = wv;
    }
    __syncthreads();
    #pragma unroll
    for (int kk = 0; kk < 16; ++kk){
      float4 av = *reinterpret_cast<const float4*>(&As[kk*68 + ty*4]);
      float4 wv = *reinterpret_cast<const float4*>(&Ws[kk*68 + tx*4]);
      float a4[4] = {av.x, av.y, av.z, av.w};
      float w4[4] = {wv.x, wv.y, wv.z, wv.w};
      #pragma unroll
      for (int i = 0; i < 4; ++i)
        #pragma unroll
        for (int j = 0; j < 4; ++j)
          acc[i][j] += a4[i]*w4[j];
    }
  }
  #pragma unroll
  for (int i = 0; i < 4; ++i){
    int lq = (m0 - q0) + ty*4 + i;
    #pragma unroll
    for (int j = 0; j < 4; ++j){
      int col = j0 + tx*4 + j;
      D[(size_t)lq*Nn + col] = n2[bN + col] - 2.f*acc[i][j];
    }
  }
}

// ---------- wave-per-query top-20 over a 2048-query strip ----------
__global__ __launch_bounds__(256, 4) void topk_kernel(
    const float* __restrict__ D, int bN, int q0, int* __restrict__ idx)
{
  const int lane = threadIdx.x & 63;
  const int wid  = threadIdx.x >> 6;
  const int lq   = blockIdx.x*4 + wid;          // 0..2047
  const float* row = D + (size_t)lq*Nn;

  float bd[20]; int bi[20];
  #pragma unroll
  for (int l = 0; l < 20; ++l){ bd[l] = 1e30f; bi[l] = 0x7fffffff; }
  float worst = 1e30f; int wp = 0;

  // per-lane top-20 of its 64 strided candidates (coalesced reads)
  for (int t = 0; t < 64; ++t){
    int j = t*64 + lane;
    float d = row[j];
    if (d < worst){
      #pragma unroll
      for (int l = 0; l < 20; ++l) if (l == wp){ bd[l] = d; bi[l] = j; }
      worst = bd[0]; wp = 0;
      #pragma unroll
      for (int l = 1; l < 20; ++l) if (bd[l] > worst){ worst = bd[l]; wp = l; }
    }
  }

  // 20 extraction rounds: wave-wide lexicographic (d, idx) min
  int mine = 0;
  #pragma unroll 1
  for (int r = 0; r < 20; ++r){
    float md = 1e30f; int mi_ = 0x7fffffff;
    #pragma unroll
    for (int l = 0; l < 20; ++l){
      bool b = (bd[l] < md) || (bd[l] == md && bi[l] < mi_);
      md  = b ? bd[l] : md;
      mi_ = b ? bi[l] : mi_;
    }
    #pragma unroll
    for (int off = 32; off >= 1; off >>= 1){
      float od = __shfl_xor(md, off, 64);
      int   oi = __shfl_xor(mi_, off, 64);
      bool b = (od < md) || (od == md && oi < mi_);
      md  = b ? od : md;
      mi_ = b ? oi : mi_;
    }
    if (lane == r) mine = mi_;
    #pragma unroll
    for (int l = 0; l < 20; ++l)
      if (bd[l] == md && bi[l] == mi_){ bd[l] = 1e30f; bi[l] = 0x7fffffff; }
  }
  if (lane < 20) idx[(size_t)(bN + q0 + lq)*Kk + lane] = mine;
}

// ---------- prepare edgeconv weights (fp32 in): wcat = [w_d ; w_x - w_d] ----------
__global__ void prep_w_kernel(const float* __restrict__ w, int C, int o0, int Osub,
                              float* __restrict__ wcat){
  int t = blockIdx.x*256 + threadIdx.x;
  if (t >= Osub*C) return;
  int o = t / C, c = t - o*C;
  int og = o0 + o;
  float wd = w[og*2*C + c];
  float wx = w[og*2*C + C + c];
  wcat[o*C + c] = wd;
  wcat[(Osub+o)*C + c] = wx - wd;
}

// ---------- gather-max epilogue of edgeconv ----------
__global__ void gathermax_kernel(const float* __restrict__ tb, const int* __restrict__ idx,
                                 const float* __restrict__ sv, const float* __restrict__ bv,
                                 int O, float* __restrict__ out, int ldo)
{
  int t = blockIdx.x*256 + threadIdx.x;
  int o = t % O;
  int m = t / O;           // b*N + i
  int b = m / Nn;
  const int twoO = 2*O;
  const int* ip = idx + (size_t)m*Kk;
  float mx = -1e30f;
  for (int j = 0; j < Kk; ++j){
    int jj = ip[j] & (Nn-1);
    mx = fmaxf(mx, tb[(size_t)(b*Nn + jj)*twoO + o]);
  }
  float basev = tb[(size_t)m*twoO + O + o];
  float y = (mx + basev) * sv[o] + bv[o];
  out[(size_t)m*ldo + o] = lrelu_f(y);
}

// ---------- ordered-uint float max keys ----------
__device__ __forceinline__ unsigned fkey(float f){
  unsigned u = __float_as_uint(f);
  return (u & 0x80000000u) ? ~u : (u | 0x80000000u);
}
__device__ __forceinline__ float funkey(unsigned k){
  if (k == 0u) return -1e30f;
  unsigned u = (k & 0x80000000u) ? (k ^ 0x80000000u) : ~k;
  return __uint_as_float(u);
}

// ---------- generic fp32 GEMM: C[M,O] = A[M,K] @ W[O,K]^T (+epilogue / pool) ----------
__global__ __launch_bounds__(256) void gemm_kernel(
    const float* __restrict__ A, int lda,
    const float* __restrict__ W, int ldw,
    float* __restrict__ Cf, int ldc,
    int K, int O,
    const float* __restrict__ scale, const float* __restrict__ bias,
    const float* __restrict__ addvec, int lrelu_flag,
    unsigned* __restrict__ pool)
{
  const int tid = threadIdx.x;
  const int tx = tid & 15, ty = tid >> 4;
  const int m0 = blockIdx.y * 64;
  const int o0 = blockIdx.x * 64;
  __shared__ __align__(16) float As[16*68];
  __shared__ __align__(16) float Ws[16*68];
  float acc[4][4] = {};
  for (int k0 = 0; k0 < K; k0 += 16){
    __syncthreads();
    #pragma unroll
    for (int r = 0; r < 4; ++r){
      int e = tid + r*256;
      int k = e & 15, mi = e >> 4;
      int kk = k0 + k;
      float v = 0.f, wv = 0.f;
      if (kk < K) v = A[(size_t)(m0+mi)*lda + kk];
      int oo = o0 + mi;
      if (kk < K && oo < O) wv = W[(size_t)oo*ldw + kk];
      As[k*68 + mi] = v;
      Ws[k*68 + mi] = wv;
    }
    __syncthreads();
    #pragma unroll
    for (int kk = 0; kk < 16; ++kk){
      float4 av = *reinterpret_cast<const float4*>(&As[kk*68 + ty*4]);
      float4 wv = *reinterpret_cast<const float4*>(&Ws[kk*68 + tx*4]);
      float a4[4] = {av.x, av.y, av.z, av.w};
      float w4[4] = {wv.x, wv.y, wv.z, wv.w};
      #pragma unroll
      for (int i = 0; i < 4; ++i)
        #pragma unroll
        for (int j = 0; j < 4; ++j)
          acc[i][j] += a4[i]*w4[j];
    }
  }
  const int b = m0 / Nn;
  if (pool){
    float cm[4];
    #pragma unroll
    for (int j = 0; j < 4; ++j){
      int o = o0 + tx*4 + j;
      float m = -1e30f;
      #pragma unroll
      for (int i = 0; i < 4; ++i){
        float y = acc[i][j];
        if (addvec) y += addvec[b*O + o];
        y = y*scale[o] + bias[o];
        y = lrelu_f(y);
        m = fmaxf(m, y);
      }
      cm[j] = m;
    }
    __syncthreads();
    #pragma unroll
    for (int j = 0; j < 4; ++j) As[ty*68 + tx*4 + j] = cm[j];
    __syncthreads();
    if (tid < 64){
      float m = -1e30f;
      #pragma unroll
      for (int r = 0; r < 16; ++r) m = fmaxf(m, As[r*68 + tid]);
      atomicMax(&pool[b*O + o0 + tid], fkey(m));
    }
    return;
  }
  #pragma unroll
  for (int i = 0; i < 4; ++i){
    int m = m0 + ty*4 + i;
    #pragma unroll
    for (int j = 0; j < 4; ++j){
      int o = o0 + tx*4 + j;
      if (o >= O) continue;
      float y = acc[i][j];
      if (addvec) y += addvec[b*O + o];
      if (scale)  y = y*scale[o] + bias[o];
      else if (bias) y += bias[o];
      if (lrelu_flag) y = lrelu_f(y);
      Cf[(size_t)m*ldc + o] = y;
    }
  }
}

__global__ void init_u32_kernel(unsigned* __restrict__ p, int n){
  int t = blockIdx.x*256 + threadIdx.x;
  if (t < n) p[t] = 0u;
}
// gvec[b,o2] = sum_c wh1[o2, 512+c] * glob[b,c]
__global__ void gvec_kernel(const float* __restrict__ wh1, int ldw, const unsigned* __restrict__ glob,
                            int Oe, int O2, float* __restrict__ gv){
  int o2 = threadIdx.x; int b = blockIdx.x;
  const float* wr = wh1 + (size_t)o2*ldw + 512;
  float s = 0.f;
  for (int c = 0; c < Oe; ++c) s += wr[c] * funkey(glob[b*Oe + c]);
  gv[b*O2 + o2] = s;
}

extern "C" void kernel_launch(void* const* d_in, const int* in_sizes, int n_in,
                              void* d_out, int out_size, void* d_ws, size_t ws_size,
                              hipStream_t stream) {
  (void)in_sizes; (void)n_in; (void)out_size; (void)ws_size;

  float* ws = (float*)d_ws;
  size_t off = 0;
  auto alloc = [&](size_t n){ float* p = ws + off; off += n; return p; };
  int*   dflag = (int*)alloc(16);
  float* xyzf = alloc((size_t)Mm*3);
  float* w1f  = alloc(64*6);
  float* w2f  = alloc(64*128);
  float* w3f  = alloc(128*256);
  float* w4f  = alloc(256*512);
  float* wff  = alloc(512*512);
  float* wef  = alloc(1024*512);
  float* wh1f = alloc(256*1536);
  float* wh2f = alloc(256*256);
  float* wh3f = alloc(50*256);
  float* wcat = alloc(512*128);
  float* nrm  = alloc(Mm);
  int*   idx  = (int*)alloc((size_t)Mm*Kk);
  unsigned* glob = (unsigned*)alloc(4096);
  float* gv   = alloc(1024);
  float* sfv = alloc(512);  float* bfv = alloc(512);
  float* sev = alloc(1024); float* bev = alloc(1024);
  float* sh1v = alloc(256); float* bh1v = alloc(256);
  float* sh2v = alloc(256); float* bh2v = alloc(256);
  float* bh3v = alloc(64);
  float* s1v = alloc(64);  float* b1v = alloc(64);
  float* s2v = alloc(64);  float* b2v = alloc(64);
  float* s3v = alloc(128); float* b3v = alloc(128);
  float* s4v = alloc(256); float* b4v = alloc(256);
  // big regions
  float* xcat = ws + 2000000;              // [M,512]
  float* regC = ws + 10400000;             // 8.39M floats multipurpose
  float* Dbuf  = regC;                     // [2048, 4096] distance strip
  float* tb    = regC;                     // [M, <=256]
  float* xloc  = regC;                     // [M,512]
  float* logitsF = regC;                   // [M,50]
  float* h1 = xcat;                        // [M,256]
  float* h2 = xcat + (size_t)Mm*256;       // [M,256]

  // ---- dtype detect, then flag-gated conversions ----
  detect_kernel<<<1, 256, 0, stream>>>(d_in[0], Mm*3, dflag);
  auto cvt = [&](int i, float* dst, int n){
    load_input_kernel<<<(n+255)/256, 256, 0, stream>>>(d_in[i], dflag, dst, n);
  };
  cvt(0, xyzf, Mm*3);
  cvt(2, w1f, 64*6);    cvt(3, s1v, 64);   cvt(4, b1v, 64);
  cvt(5, w2f, 64*128);  cvt(6, s2v, 64);   cvt(7, b2v, 64);
  cvt(8, w3f, 128*256); cvt(9, s3v, 128);  cvt(10, b3v, 128);
  cvt(11, w4f, 256*512);cvt(12, s4v, 256); cvt(13, b4v, 256);
  cvt(14, wff, 512*512);  cvt(15, sfv, 512);  cvt(16, bfv, 512);
  cvt(17, wef, 1024*512); cvt(18, sev, 1024); cvt(19, bev, 1024);
  cvt(20, wh1f, 256*1536);cvt(21, sh1v, 256); cvt(22, bh1v, 256);
  cvt(23, wh2f, 256*256); cvt(24, sh2v, 256); cvt(25, bh2v, 256);
  cvt(26, wh3f, 50*256);  cvt(27, bh3v, 50);
  init_u32_kernel<<<16, 256, 0, stream>>>(glob, 4096);

  auto gemm = [&](const float* A, int lda, const float* W, int ldw,
                  float* Cf, int ldc, int K, int O,
                  const float* sc, const float* bi, const float* av, int lr,
                  unsigned* pool){
    dim3 g((O+63)/64, Mm/64);
    gemm_kernel<<<g, 256, 0, stream>>>(A, lda, W, ldw, Cf, ldc, K, O, sc, bi, av, lr, pool);
  };

  auto edgeconv = [&](const float* xin, int ld, int C, int O,
                      const float* w, const float* sv, const float* bv,
                      float* xout, int ldo){
    norms_kernel<<<Mm/256, 256, 0, stream>>>(xin, ld, C, Mm, nrm);
    // KNN: per (batch, half) strip: distance GEMM then wave-per-query top-20
    for (int b = 0; b < Bb; ++b){
      for (int h = 0; h < 2; ++h){
        int q0 = h*2048;
        dist_kernel<<<dim3(64, 32), 256, 0, stream>>>(xin, ld, C, nrm, b*Nn, q0, Dbuf);
        topk_kernel<<<512, 256, 0, stream>>>(Dbuf, b*Nn, q0, idx);
      }
    }
    int chunk = (O > 128) ? 128 : O;
    for (int o0 = 0; o0 < O; o0 += chunk){
      int Osub = chunk;
      prep_w_kernel<<<(Osub*C+255)/256, 256, 0, stream>>>(w, C, o0, Osub, wcat);
      gemm(xin, ld, wcat, C, tb, 2*Osub, C, 2*Osub, nullptr, nullptr, nullptr, 0, nullptr);
      gathermax_kernel<<<((size_t)Mm*Osub)/256, 256, 0, stream>>>(
          tb, idx, sv + o0, bv + o0, Osub, xout + o0, ldo);
    }
  };

  edgeconv(xyzf, 3, 3, 64,            w1f, s1v, b1v, xcat + 0,   512);
  edgeconv(xcat + 0,   512, 64, 64,   w2f, s2v, b2v, xcat + 64,  512);
  edgeconv(xcat + 64,  512, 64, 128,  w3f, s3v, b3v, xcat + 128, 512);
  edgeconv(xcat + 128, 512, 128, 256, w4f, s4v, b4v, xcat + 256, 512);

  // x_local = lrelu((x_cat @ wf^T)*sf + bf)
  gemm(xcat, 512, wff, 512, xloc, 512, 512, 512, sfv, bfv, nullptr, 1, nullptr);
  // x_emb GEMM fused with global max pool -> glob
  gemm(xloc, 512, wef, 512, nullptr, 0, 512, 1024, sev, bev, nullptr, 1, glob);
  gvec_kernel<<<Bb, 256, 0, stream>>>(wh1f, 1536, glob, 1024, 256, gv);
  // h1 = lrelu((x_local @ wh1[:, :512]^T + gvec)*sh1 + bh1)
  gemm(xloc, 512, wh1f, 1536, h1, 256, 512, 256, sh1v, bh1v, gv, 1, nullptr);
  // h2
  gemm(h1, 256, wh2f, 256, h2, 256, 256, 256, sh2v, bh2v, nullptr, 1, nullptr);
  // logits (fp32 scratch), then flag-gated store to d_out
  gemm(h2, 256, wh3f, 256, logitsF, 50, 256, 50, nullptr, bh3v, nullptr, 0, nullptr);
  store_out_kernel<<<((size_t)Mm*50 + 255)/256, 256, 0, stream>>>(logitsF, dflag, d_out, Mm*50);
}

// Round 5
// 3971.029 us; speedup vs baseline: 1.2139x; 1.2139x over previous
//
#include <hip/hip_runtime.h>
#include <hip/hip_bf16.h>
#include <cstdint>

#define LEAKV 0.2f
static const int Bb = 4, Nn = 4096, Mm = 16384, Kk = 20;

__device__ __forceinline__ float lrelu_f(float v){ return v > 0.f ? v : LEAKV*v; }

// ---------- dtype detector: read as bf16, count wild values ----------
__global__ void detect_kernel(const void* __restrict__ xyz, int n, int* __restrict__ flag){
  __shared__ int cnt;
  if (threadIdx.x == 0) cnt = 0;
  __syncthreads();
  const __hip_bfloat16* p = (const __hip_bfloat16*)xyz;
  int local = 0;
  for (int i = threadIdx.x; i < n; i += 256){
    float v = __bfloat162float(p[i]);
    if (!(fabsf(v) < 1000.f)) local++;
  }
  atomicAdd(&cnt, local);
  __syncthreads();
  if (threadIdx.x == 0) *flag = (cnt < n/16) ? 1 : 0;   // 1 = bf16, 0 = fp32
}

// ---------- flag-gated input load -> fp32 ----------
__global__ void load_input_kernel(const void* __restrict__ src, const int* __restrict__ flag,
                                  float* __restrict__ out, int n){
  int t = blockIdx.x*256 + threadIdx.x;
  if (t >= n) return;
  if (*flag) out[t] = __bfloat162float(((const __hip_bfloat16*)src)[t]);
  else       out[t] = ((const float*)src)[t];
}

// ---------- flag-gated output store ----------
__global__ void store_out_kernel(const float* __restrict__ src, const int* __restrict__ flag,
                                 void* __restrict__ dst, int n){
  int t = blockIdx.x*256 + threadIdx.x;
  if (t >= n) return;
  float v = src[t];
  if (*flag) ((__hip_bfloat16*)dst)[t] = __float2bfloat16(v);
  else       ((float*)dst)[t] = v;
}

// ---------- squared norms ----------
__global__ void norms_kernel(const float* __restrict__ x, int ld, int C, int total, float* __restrict__ out){
  int t = blockIdx.x*256 + threadIdx.x;
  if (t >= total) return;
  const float* r = x + (size_t)t*ld;
  float s = 0.f;
  for (int c = 0; c < C; ++c){ float v = r[c]; s += v*v; }
  out[t] = s;
}

// ---------- fused KNN: 64 queries/block, distances tiled through LDS, top-20 in regs ----------
template<int C>
__global__ __launch_bounds__(256, 1) void knn_fused_kernel(
    const float* __restrict__ x, int ld, const float* __restrict__ n2,
    int* __restrict__ idx)
{
  constexpr int CP = (C + 15) & ~15;
  constexpr unsigned SZ_A = CP*68*4;
  constexpr unsigned SZ_B = 16*68*4;
  constexpr unsigned SZ_D = 64*65*4;
  constexpr unsigned SZ_S = 64*4;
  constexpr unsigned SZ_MAIN = SZ_A + SZ_B + SZ_D + SZ_S;
  constexpr unsigned SZ_MERGE = 256*20*8;
  constexpr unsigned SZ = SZ_MAIN > SZ_MERGE ? SZ_MAIN : SZ_MERGE;
  __shared__ __align__(16) char smem[SZ];
  float* As = (float*)smem;                        // [CP][68] query dims
  float* Bs = (float*)(smem + SZ_A);               // [16][68] cand k-slab
  float* Dt = (float*)(smem + SZ_A + SZ_B);        // [64][65] distance tile
  float* sn = (float*)(smem + SZ_A + SZ_B + SZ_D); // [64] cand norms
  float* mbd = (float*)smem;                       // merge: [256][20]
  int*   mbi = (int*)(smem + 256*20*4);

  const int tid = threadIdx.x;
  const int tx = tid & 15, ty = tid >> 4;
  const int b = blockIdx.y, bN = b*Nn;
  const int q0 = blockIdx.x*64;

  // stage queries once: As[k][q]
  for (int e = tid; e < 64*CP; e += 256){
    int q = e / CP, k = e - q*CP;
    float v = (k < C) ? x[(size_t)(bN + q0 + q)*ld + k] : 0.f;
    As[k*68 + q] = v;
  }

  float bd[20]; int bi[20];
  #pragma unroll
  for (int l = 0; l < 20; ++l){ bd[l] = 1e30f; bi[l] = 0x7fffffff; }
  float worst = 1e30f; int wp = 0;

  for (int jt = 0; jt < 64; ++jt){
    const int j0 = jt*64;
    float acc[4][4] = {};
    for (int k0 = 0; k0 < CP; k0 += 16){
      __syncthreads();                     // Bs safe to overwrite; also fences prev scan
      #pragma unroll
      for (int r = 0; r < 4; ++r){
        int e = tid + r*256;
        int k = e & 15, mi = e >> 4;
        int kk = k0 + k;
        float v = (kk < C) ? x[(size_t)(bN + j0 + mi)*ld + kk] : 0.f;
        Bs[k*68 + mi] = v;
      }
      if (k0 == 0 && tid < 64) sn[tid] = n2[bN + j0 + tid];
      __syncthreads();
      #pragma unroll
      for (int kk = 0; kk < 16; ++kk){
        float4 av = *reinterpret_cast<const float4*>(&As[(k0+kk)*68 + ty*4]);
        float4 wv = *reinterpret_cast<const float4*>(&Bs[kk*68 + tx*4]);
        float a4[4] = {av.x, av.y, av.z, av.w};
        float w4[4] = {wv.x, wv.y, wv.z, wv.w};
        #pragma unroll
        for (int i = 0; i < 4; ++i)
          #pragma unroll
          for (int j = 0; j < 4; ++j)
            acc[i][j] += a4[i]*w4[j];
      }
    }
    // deposit distance tile
    #pragma unroll
    for (int i = 0; i < 4; ++i)
      #pragma unroll
      for (int j = 0; j < 4; ++j)
        Dt[(ty*4+i)*65 + tx*4+j] = sn[tx*4+j] - 2.f*acc[i][j];
    __syncthreads();
    // scan: 4 threads per query, 16 cands each
    {
      const int q = tid >> 2, p16 = (tid & 3)*16;
      const float* row = Dt + q*65 + p16;
      #pragma unroll
      for (int t = 0; t < 16; ++t){
        float d = row[t];
        if (d < worst){
          int j = j0 + p16 + t;
          #pragma unroll
          for (int l = 0; l < 20; ++l) if (l == wp){ bd[l] = d; bi[l] = j; }
          worst = bd[0]; wp = 0;
          #pragma unroll
          for (int l = 1; l < 20; ++l) if (bd[l] > worst){ worst = bd[l]; wp = l; }
        }
      }
    }
  }
  // merge 4 partial lists per query
  __syncthreads();
  #pragma unroll
  for (int l = 0; l < 20; ++l){ mbd[tid*20 + l] = bd[l]; mbi[tid*20 + l] = bi[l]; }
  __syncthreads();
  if (tid < 64){
    float fd[20]; int fi[20];
    #pragma unroll
    for (int l = 0; l < 20; ++l){ fd[l] = 1e30f; fi[l] = 0x7fffffff; }
    float wd_ = 1e30f; int wi_ = 0x7fffffff, wp_ = 0;
    for (int e = 0; e < 80; ++e){
      int p = e / 20, l0 = e - p*20;
      float d = mbd[(tid*4 + p)*20 + l0];
      int   id = mbi[(tid*4 + p)*20 + l0];
      bool better = (d < wd_) || (d == wd_ && id < wi_);
      if (better){
        #pragma unroll
        for (int l = 0; l < 20; ++l) if (l == wp_){ fd[l] = d; fi[l] = id; }
        wd_ = fd[0]; wi_ = fi[0]; wp_ = 0;
        #pragma unroll
        for (int l = 1; l < 20; ++l)
          if (fd[l] > wd_ || (fd[l] == wd_ && fi[l] > wi_)){ wd_ = fd[l]; wi_ = fi[l]; wp_ = l; }
      }
    }
    #pragma unroll
    for (int l = 0; l < 20; ++l) idx[(size_t)(bN + q0 + tid)*Kk + l] = fi[l];
  }
}

// ---------- prepare edgeconv weights (fp32 in): wcat = [w_d ; w_x - w_d] ----------
__global__ void prep_w_kernel(const float* __restrict__ w, int C, int o0, int Osub,
                              float* __restrict__ wcat){
  int t = blockIdx.x*256 + threadIdx.x;
  if (t >= Osub*C) return;
  int o = t / C, c = t - o*C;
  int og = o0 + o;
  float wd = w[og*2*C + c];
  float wx = w[og*2*C + C + c];
  wcat[o*C + c] = wd;
  wcat[(Osub+o)*C + c] = wx - wd;
}

// ---------- gather-max epilogue of edgeconv ----------
__global__ void gathermax_kernel(const float* __restrict__ tb, const int* __restrict__ idx,
                                 const float* __restrict__ sv, const float* __restrict__ bv,
                                 int O, float* __restrict__ out, int ldo)
{
  int t = blockIdx.x*256 + threadIdx.x;
  int o = t % O;
  int m = t / O;           // b*N + i
  int b = m / Nn;
  const int twoO = 2*O;
  const int* ip = idx + (size_t)m*Kk;
  float mx = -1e30f;
  for (int j = 0; j < Kk; ++j){
    int jj = ip[j] & (Nn-1);
    mx = fmaxf(mx, tb[(size_t)(b*Nn + jj)*twoO + o]);
  }
  float basev = tb[(size_t)m*twoO + O + o];
  float y = (mx + basev) * sv[o] + bv[o];
  out[(size_t)m*ldo + o] = lrelu_f(y);
}

// ---------- ordered-uint float max keys ----------
__device__ __forceinline__ unsigned fkey(float f){
  unsigned u = __float_as_uint(f);
  return (u & 0x80000000u) ? ~u : (u | 0x80000000u);
}
__device__ __forceinline__ float funkey(unsigned k){
  if (k == 0u) return -1e30f;
  unsigned u = (k & 0x80000000u) ? (k ^ 0x80000000u) : ~k;
  return __uint_as_float(u);
}

// ---------- generic fp32 GEMM: C[M,O] = A[M,K] @ W[O,K]^T (+epilogue / pool) ----------
__global__ __launch_bounds__(256) void gemm_kernel(
    const float* __restrict__ A, int lda,
    const float* __restrict__ W, int ldw,
    float* __restrict__ Cf, int ldc,
    int K, int O,
    const float* __restrict__ scale, const float* __restrict__ bias,
    const float* __restrict__ addvec, int lrelu_flag,
    unsigned* __restrict__ pool)
{
  const int tid = threadIdx.x;
  const int tx = tid & 15, ty = tid >> 4;
  const int m0 = blockIdx.y * 64;
  const int o0 = blockIdx.x * 64;
  __shared__ __align__(16) float As[16*68];
  __shared__ __align__(16) float Ws[16*68];
  float acc[4][4] = {};
  for (int k0 = 0; k0 < K; k0 += 16){
    __syncthreads();
    #pragma unroll
    for (int r = 0; r < 4; ++r){
      int e = tid + r*256;
      int k = e & 15, mi = e >> 4;
      int kk = k0 + k;
      float v = 0.f, wv = 0.f;
      if (kk < K) v = A[(size_t)(m0+mi)*lda + kk];
      int oo = o0 + mi;
      if (kk < K && oo < O) wv = W[(size_t)oo*ldw + kk];
      As[k*68 + mi] = v;
      Ws[k*68 + mi] = wv;
    }
    __syncthreads();
    #pragma unroll
    for (int kk = 0; kk < 16; ++kk){
      float4 av = *reinterpret_cast<const float4*>(&As[kk*68 + ty*4]);
      float4 wv = *reinterpret_cast<const float4*>(&Ws[kk*68 + tx*4]);
      float a4[4] = {av.x, av.y, av.z, av.w};
      float w4[4] = {wv.x, wv.y, wv.z, wv.w};
      #pragma unroll
      for (int i = 0; i < 4; ++i)
        #pragma unroll
        for (int j = 0; j < 4; ++j)
          acc[i][j] += a4[i]*w4[j];
    }
  }
  const int b = m0 / Nn;
  if (pool){
    float cm[4];
    #pragma unroll
    for (int j = 0; j < 4; ++j){
      int o = o0 + tx*4 + j;
      float m = -1e30f;
      #pragma unroll
      for (int i = 0; i < 4; ++i){
        float y = acc[i][j];
        if (addvec) y += addvec[b*O + o];
        y = y*scale[o] + bias[o];
        y = lrelu_f(y);
        m = fmaxf(m, y);
      }
      cm[j] = m;
    }
    __syncthreads();
    #pragma unroll
    for (int j = 0; j < 4; ++j) As[ty*68 + tx*4 + j] = cm[j];
    __syncthreads();
    if (tid < 64){
      float m = -1e30f;
      #pragma unroll
      for (int r = 0; r < 16; ++r) m = fmaxf(m, As[r*68 + tid]);
      atomicMax(&pool[b*O + o0 + tid], fkey(m));
    }
    return;
  }
  #pragma unroll
  for (int i = 0; i < 4; ++i){
    int m = m0 + ty*4 + i;
    #pragma unroll
    for (int j = 0; j < 4; ++j){
      int o = o0 + tx*4 + j;
      if (o >= O) continue;
      float y = acc[i][j];
      if (addvec) y += addvec[b*O + o];
      if (scale)  y = y*scale[o] + bias[o];
      else if (bias) y += bias[o];
      if (lrelu_flag) y = lrelu_f(y);
      Cf[(size_t)m*ldc + o] = y;
    }
  }
}

__global__ void init_u32_kernel(unsigned* __restrict__ p, int n){
  int t = blockIdx.x*256 + threadIdx.x;
  if (t < n) p[t] = 0u;
}
// gvec[b,o2] = sum_c wh1[o2, 512+c] * glob[b,c]
__global__ void gvec_kernel(const float* __restrict__ wh1, int ldw, const unsigned* __restrict__ glob,
                            int Oe, int O2, float* __restrict__ gv){
  int o2 = threadIdx.x; int b = blockIdx.x;
  const float* wr = wh1 + (size_t)o2*ldw + 512;
  float s = 0.f;
  for (int c = 0; c < Oe; ++c) s += wr[c] * funkey(glob[b*Oe + c]);
  gv[b*O2 + o2] = s;
}

extern "C" void kernel_launch(void* const* d_in, const int* in_sizes, int n_in,
                              void* d_out, int out_size, void* d_ws, size_t ws_size,
                              hipStream_t stream) {
  (void)in_sizes; (void)n_in; (void)out_size; (void)ws_size;

  float* ws = (float*)d_ws;
  size_t off = 0;
  auto alloc = [&](size_t n){ float* p = ws + off; off += n; return p; };
  int*   dflag = (int*)alloc(16);
  float* xyzf = alloc((size_t)Mm*3);
  float* w1f  = alloc(64*6);
  float* w2f  = alloc(64*128);
  float* w3f  = alloc(128*256);
  float* w4f  = alloc(256*512);
  float* wff  = alloc(512*512);
  float* wef  = alloc(1024*512);
  float* wh1f = alloc(256*1536);
  float* wh2f = alloc(256*256);
  float* wh3f = alloc(50*256);
  float* wcat = alloc(512*128);
  float* nrm  = alloc(Mm);
  int*   idx  = (int*)alloc((size_t)Mm*Kk);
  unsigned* glob = (unsigned*)alloc(4096);
  float* gv   = alloc(1024);
  float* sfv = alloc(512);  float* bfv = alloc(512);
  float* sev = alloc(1024); float* bev = alloc(1024);
  float* sh1v = alloc(256); float* bh1v = alloc(256);
  float* sh2v = alloc(256); float* bh2v = alloc(256);
  float* bh3v = alloc(64);
  float* s1v = alloc(64);  float* b1v = alloc(64);
  float* s2v = alloc(64);  float* b2v = alloc(64);
  float* s3v = alloc(128); float* b3v = alloc(128);
  float* s4v = alloc(256); float* b4v = alloc(256);
  // big regions
  float* xcat = ws + 2000000;              // [M,512] fp32
  float* regC = ws + 10400000;             // 8.39M floats multipurpose
  float* tb    = regC;                     // [M, <=256] fp32
  float* xloc  = regC;                     // [M,512] fp32
  float* logitsF = regC;                   // [M,50]
  float* h1 = xcat;                        // [M,256] (xcat dead after wf GEMM)
  float* h2 = xcat + (size_t)Mm*256;       // [M,256]

  // ---- dtype detect, then flag-gated conversions ----
  detect_kernel<<<1, 256, 0, stream>>>(d_in[0], Mm*3, dflag);
  auto cvt = [&](int i, float* dst, int n){
    load_input_kernel<<<(n+255)/256, 256, 0, stream>>>(d_in[i], dflag, dst, n);
  };
  cvt(0, xyzf, Mm*3);
  cvt(2, w1f, 64*6);    cvt(3, s1v, 64);   cvt(4, b1v, 64);
  cvt(5, w2f, 64*128);  cvt(6, s2v, 64);   cvt(7, b2v, 64);
  cvt(8, w3f, 128*256); cvt(9, s3v, 128);  cvt(10, b3v, 128);
  cvt(11, w4f, 256*512);cvt(12, s4v, 256); cvt(13, b4v, 256);
  cvt(14, wff, 512*512);  cvt(15, sfv, 512);  cvt(16, bfv, 512);
  cvt(17, wef, 1024*512); cvt(18, sev, 1024); cvt(19, bev, 1024);
  cvt(20, wh1f, 256*1536);cvt(21, sh1v, 256); cvt(22, bh1v, 256);
  cvt(23, wh2f, 256*256); cvt(24, sh2v, 256); cvt(25, bh2v, 256);
  cvt(26, wh3f, 50*256);  cvt(27, bh3v, 50);
  init_u32_kernel<<<16, 256, 0, stream>>>(glob, 4096);

  auto gemm = [&](const float* A, int lda, const float* W, int ldw,
                  float* Cf, int ldc, int K, int O,
                  const float* sc, const float* bi, const float* av, int lr,
                  unsigned* pool){
    dim3 g((O+63)/64, Mm/64);
    gemm_kernel<<<g, 256, 0, stream>>>(A, lda, W, ldw, Cf, ldc, K, O, sc, bi, av, lr, pool);
  };

  auto edgeconv = [&](const float* xin, int ld, int C, int O,
                      const float* w, const float* sv, const float* bv,
                      float* xout, int ldo){
    norms_kernel<<<Mm/256, 256, 0, stream>>>(xin, ld, C, Mm, nrm);
    dim3 g(Nn/64, Bb);
    if (C == 3)       knn_fused_kernel<3><<<g, 256, 0, stream>>>(xin, ld, nrm, idx);
    else if (C == 64) knn_fused_kernel<64><<<g, 256, 0, stream>>>(xin, ld, nrm, idx);
    else              knn_fused_kernel<128><<<g, 256, 0, stream>>>(xin, ld, nrm, idx);
    int chunk = (O > 128) ? 128 : O;
    for (int o0 = 0; o0 < O; o0 += chunk){
      int Osub = chunk;
      prep_w_kernel<<<(Osub*C+255)/256, 256, 0, stream>>>(w, C, o0, Osub, wcat);
      gemm(xin, ld, wcat, C, tb, 2*Osub, C, 2*Osub, nullptr, nullptr, nullptr, 0, nullptr);
      gathermax_kernel<<<((size_t)Mm*Osub)/256, 256, 0, stream>>>(
          tb, idx, sv + o0, bv + o0, Osub, xout + o0, ldo);
    }
  };

  edgeconv(xyzf, 3, 3, 64,            w1f, s1v, b1v, xcat + 0,   512);
  edgeconv(xcat + 0,   512, 64, 64,   w2f, s2v, b2v, xcat + 64,  512);
  edgeconv(xcat + 64,  512, 64, 128,  w3f, s3v, b3v, xcat + 128, 512);
  edgeconv(xcat + 128, 512, 128, 256, w4f, s4v, b4v, xcat + 256, 512);

  // x_local = lrelu((x_cat @ wf^T)*sf + bf)
  gemm(xcat, 512, wff, 512, xloc, 512, 512, 512, sfv, bfv, nullptr, 1, nullptr);
  // x_emb GEMM fused with global max pool -> glob
  gemm(xloc, 512, wef, 512, nullptr, 0, 512, 1024, sev, bev, nullptr, 1, glob);
  gvec_kernel<<<Bb, 256, 0, stream>>>(wh1f, 1536, glob, 1024, 256, gv);
  // h1 = lrelu((x_local @ wh1[:, :512]^T + gvec)*sh1 + bh1)
  gemm(xloc, 512, wh1f, 1536, h1, 256, 512, 256, sh1v, bh1v, gv, 1, nullptr);
  // h2
  gemm(h1, 256, wh2f, 256, h2, 256, 256, 256, sh2v, bh2v, nullptr, 1, nullptr);
  // logits (fp32 scratch), then flag-gated store to d_out
  gemm(h2, 256, wh3f, 256, logitsF, 50, 256, 50, nullptr, bh3v, nullptr, 0, nullptr);
  store_out_kernel<<<((size_t)Mm*50 + 255)/256, 256, 0, stream>>>(logitsF, dflag, d_out, Mm*50);
}

// Round 6
// 3241.967 us; speedup vs baseline: 1.4869x; 1.2249x over previous
//
#include <hip/hip_runtime.h>
#include <hip/hip_bf16.h>
#include <cstdint>

#define LEAKV 0.2f
static const int Bb = 4, Nn = 4096, Mm = 16384, Kk = 20;

__device__ __forceinline__ float lrelu_f(float v){ return v > 0.f ? v : LEAKV*v; }

// ---------- dtype detector: read as bf16, count wild values ----------
__global__ void detect_kernel(const void* __restrict__ xyz, int n, int* __restrict__ flag){
  __shared__ int cnt;
  if (threadIdx.x == 0) cnt = 0;
  __syncthreads();
  const __hip_bfloat16* p = (const __hip_bfloat16*)xyz;
  int local = 0;
  for (int i = threadIdx.x; i < n; i += 256){
    float v = __bfloat162float(p[i]);
    if (!(fabsf(v) < 1000.f)) local++;
  }
  atomicAdd(&cnt, local);
  __syncthreads();
  if (threadIdx.x == 0) *flag = (cnt < n/16) ? 1 : 0;   // 1 = bf16, 0 = fp32
}

// ---------- flag-gated input load -> fp32 ----------
__global__ void load_input_kernel(const void* __restrict__ src, const int* __restrict__ flag,
                                  float* __restrict__ out, int n){
  int t = blockIdx.x*256 + threadIdx.x;
  if (t >= n) return;
  if (*flag) out[t] = __bfloat162float(((const __hip_bfloat16*)src)[t]);
  else       out[t] = ((const float*)src)[t];
}

// ---------- flag-gated output store ----------
__global__ void store_out_kernel(const float* __restrict__ src, const int* __restrict__ flag,
                                 void* __restrict__ dst, int n){
  int t = blockIdx.x*256 + threadIdx.x;
  if (t >= n) return;
  float v = src[t];
  if (*flag) ((__hip_bfloat16*)dst)[t] = __float2bfloat16(v);
  else       ((float*)dst)[t] = v;
}

// ---------- squared norms ----------
__global__ void norms_kernel(const float* __restrict__ x, int ld, int C, int total, float* __restrict__ out){
  int t = blockIdx.x*256 + threadIdx.x;
  if (t >= total) return;
  const float* r = x + (size_t)t*ld;
  float s = 0.f;
  for (int c = 0; c < C; ++c){ float v = r[c]; s += v*v; }
  out[t] = s;
}

// ---------- candidate-split KNN (C=64/128): 64 queries x Nn/G cands per block ----------
template<int C, int G>
__global__ __launch_bounds__(256, 4) void knn_split_kernel(
    const float* __restrict__ x, int ld, const float* __restrict__ n2,
    float* __restrict__ outd, int* __restrict__ outi)
{
  constexpr int CP = (C + 15) & ~15;
  constexpr unsigned SZ_A = CP*68*4;
  constexpr unsigned SZ_B = 16*68*4;
  constexpr unsigned SZ_D = 64*68*4;
  constexpr unsigned SZ_S = 64*4;
  constexpr unsigned SZ_MAIN = SZ_A + SZ_B + SZ_D + SZ_S;
  constexpr unsigned SZ_MERGE = 20*256*8;
  constexpr unsigned SZ = SZ_MAIN > SZ_MERGE ? SZ_MAIN : SZ_MERGE;
  __shared__ __align__(16) char smem[SZ];
  float* As = (float*)smem;                        // [CP][68]
  float* Bs = (float*)(smem + SZ_A);               // [16][68]
  float* Dt = (float*)(smem + SZ_A + SZ_B);        // [64][68]
  float* sn = (float*)(smem + SZ_A + SZ_B + SZ_D); // [64]
  float* mbd = (float*)smem;                       // merge: [20][256]
  int*   mbi = (int*)(smem + 20*256*4);

  const int tid = threadIdx.x;
  const int tx = tid & 15, ty = tid >> 4;
  const int b = blockIdx.z, bN = b*Nn;
  const int q0 = blockIdx.x*64;
  const int g = blockIdx.y;
  const int NT = (Nn/G)/64;

  // stage queries once: As[k][q]
  for (int e = tid; e < 64*CP; e += 256){
    int q = e / CP, k = e - q*CP;
    float v = (k < C) ? x[(size_t)(bN + q0 + q)*ld + k] : 0.f;
    As[k*68 + q] = v;
  }

  float bd[20]; int bi[20];
  #pragma unroll
  for (int l = 0; l < 20; ++l){ bd[l] = 1e30f; bi[l] = 0x7fffffff; }
  float worst = 1e30f; int wp = 0;

  for (int jt = 0; jt < NT; ++jt){
    const int j0 = g*(Nn/G) + jt*64;
    float acc[4][4] = {};
    for (int k0 = 0; k0 < CP; k0 += 16){
      __syncthreads();
      #pragma unroll
      for (int r = 0; r < 4; ++r){
        int e = tid + r*256;
        int k = e & 15, mi = e >> 4;
        int kk = k0 + k;
        float v = (kk < C) ? x[(size_t)(bN + j0 + mi)*ld + kk] : 0.f;
        Bs[k*68 + mi] = v;
      }
      if (k0 == 0 && tid < 64) sn[tid] = n2[bN + j0 + tid];
      __syncthreads();
      #pragma unroll
      for (int kk = 0; kk < 16; ++kk){
        float4 av = *reinterpret_cast<const float4*>(&As[(k0+kk)*68 + ty*4]);
        float4 wv = *reinterpret_cast<const float4*>(&Bs[kk*68 + tx*4]);
        float a4[4] = {av.x, av.y, av.z, av.w};
        float w4[4] = {wv.x, wv.y, wv.z, wv.w};
        #pragma unroll
        for (int i = 0; i < 4; ++i)
          #pragma unroll
          for (int j = 0; j < 4; ++j)
            acc[i][j] += a4[i]*w4[j];
      }
    }
    // deposit distance tile as aligned float4 (2-way banks = free)
    #pragma unroll
    for (int i = 0; i < 4; ++i){
      float4 dv;
      dv.x = sn[tx*4+0] - 2.f*acc[i][0];
      dv.y = sn[tx*4+1] - 2.f*acc[i][1];
      dv.z = sn[tx*4+2] - 2.f*acc[i][2];
      dv.w = sn[tx*4+3] - 2.f*acc[i][3];
      *reinterpret_cast<float4*>(&Dt[(ty*4+i)*68 + tx*4]) = dv;
    }
    __syncthreads();
    // scan: 4 threads per query, 16 cands each
    {
      const int q = tid >> 2, p16 = (tid & 3)*16;
      const float* row = Dt + q*68 + p16;
      #pragma unroll
      for (int t = 0; t < 16; ++t){
        float d = row[t];
        if (d < worst){
          int j = j0 + p16 + t;
          #pragma unroll
          for (int l = 0; l < 20; ++l) if (l == wp){ bd[l] = d; bi[l] = j; }
          worst = bd[0]; wp = 0;
          #pragma unroll
          for (int l = 1; l < 20; ++l) if (bd[l] > worst){ worst = bd[l]; wp = l; }
        }
      }
    }
  }
  // in-block merge: 4 partial lists per query -> one 20-list for this group
  __syncthreads();
  #pragma unroll
  for (int l = 0; l < 20; ++l){ mbd[l*256 + tid] = bd[l]; mbi[l*256 + tid] = bi[l]; }
  __syncthreads();
  if (tid < 64){
    float fd[20]; int fi[20];
    #pragma unroll
    for (int l = 0; l < 20; ++l){ fd[l] = 1e30f; fi[l] = 0x7fffffff; }
    float wd_ = 1e30f; int wi_ = 0x7fffffff; int wp_ = 0;
    for (int e = 0; e < 80; ++e){
      int p = e >> 5 ? 0 : 0; (void)p;
      int l0 = e % 20, ps = e / 20;
      float d = mbd[l0*256 + (tid*4 + ps)];
      int   id = mbi[l0*256 + (tid*4 + ps)];
      bool better = (d < wd_) || (d == wd_ && id < wi_);
      if (better){
        #pragma unroll
        for (int l = 0; l < 20; ++l) if (l == wp_){ fd[l] = d; fi[l] = id; }
        wd_ = fd[0]; wi_ = fi[0]; wp_ = 0;
        #pragma unroll
        for (int l = 1; l < 20; ++l)
          if (fd[l] > wd_ || (fd[l] == wd_ && fi[l] > wi_)){ wd_ = fd[l]; wi_ = fi[l]; wp_ = l; }
      }
    }
    size_t base = ((size_t)(bN + q0 + tid)*G + g)*20;
    #pragma unroll
    for (int l = 0; l < 20; ++l){ outd[base + l] = fd[l]; outi[base + l] = fi[l]; }
  }
}

// ---------- KNN for C=3: 1 thread/query, candidates broadcast from LDS, G=8 ----------
__global__ __launch_bounds__(256, 4) void knn3_kernel(
    const float* __restrict__ x, const float* __restrict__ n2,
    float* __restrict__ outd, int* __restrict__ outi)
{
  __shared__ __align__(16) float cs[512*4];
  const int tid = threadIdx.x;
  const int b = blockIdx.z, bN = b*Nn;
  const int g = blockIdx.y;                 // 0..7
  const int q = blockIdx.x*256 + tid;
  float qx = x[(size_t)(bN+q)*3 + 0];
  float qy = x[(size_t)(bN+q)*3 + 1];
  float qz = x[(size_t)(bN+q)*3 + 2];
  for (int e = tid; e < 512; e += 256){
    int j = g*512 + e;
    cs[e*4+0] = x[(size_t)(bN+j)*3 + 0];
    cs[e*4+1] = x[(size_t)(bN+j)*3 + 1];
    cs[e*4+2] = x[(size_t)(bN+j)*3 + 2];
    cs[e*4+3] = n2[bN+j];
  }
  __syncthreads();
  float bd[20]; int bi[20];
  #pragma unroll
  for (int l = 0; l < 20; ++l){ bd[l] = 1e30f; bi[l] = 0x7fffffff; }
  float worst = 1e30f; int wp = 0;
  for (int t = 0; t < 512; ++t){
    float4 c = *reinterpret_cast<const float4*>(&cs[t*4]);
    float d = c.w - 2.f*(qx*c.x + qy*c.y + qz*c.z);
    if (d < worst){
      int j = g*512 + t;
      #pragma unroll
      for (int l = 0; l < 20; ++l) if (l == wp){ bd[l] = d; bi[l] = j; }
      worst = bd[0]; wp = 0;
      #pragma unroll
      for (int l = 1; l < 20; ++l) if (bd[l] > worst){ worst = bd[l]; wp = l; }
    }
  }
  size_t base = ((size_t)(bN + q)*8 + g)*20;
  #pragma unroll
  for (int l = 0; l < 20; ++l){ outd[base + l] = bd[l]; outi[base + l] = bi[l]; }
}

// ---------- final merge: G lists of 20 -> top-20 (register resident) ----------
__global__ __launch_bounds__(256, 4) void knn_final_merge_kernel(
    const float* __restrict__ ind, const int* __restrict__ ini, int G,
    int* __restrict__ idx)
{
  int t = blockIdx.x*256 + threadIdx.x;
  if (t >= Mm) return;
  size_t base = (size_t)t*G*20;
  float fd[20]; int fi[20];
  #pragma unroll
  for (int l = 0; l < 20; ++l){ fd[l] = 1e30f; fi[l] = 0x7fffffff; }
  float wd_ = 1e30f; int wi_ = 0x7fffffff; int wp_ = 0;
  for (int e = 0; e < G*20; ++e){
    float d = ind[base + e];
    int   id = ini[base + e];
    bool better = (d < wd_) || (d == wd_ && id < wi_);
    if (better){
      #pragma unroll
      for (int l = 0; l < 20; ++l) if (l == wp_){ fd[l] = d; fi[l] = id; }
      wd_ = fd[0]; wi_ = fi[0]; wp_ = 0;
      #pragma unroll
      for (int l = 1; l < 20; ++l)
        if (fd[l] > wd_ || (fd[l] == wd_ && fi[l] > wi_)){ wd_ = fd[l]; wi_ = fi[l]; wp_ = l; }
    }
  }
  #pragma unroll
  for (int l = 0; l < 20; ++l) idx[(size_t)t*Kk + l] = fi[l];
}

// ---------- prepare edgeconv weights (fp32 in): wcat = [w_d ; w_x - w_d] ----------
__global__ void prep_w_kernel(const float* __restrict__ w, int C, int o0, int Osub,
                              float* __restrict__ wcat){
  int t = blockIdx.x*256 + threadIdx.x;
  if (t >= Osub*C) return;
  int o = t / C, c = t - o*C;
  int og = o0 + o;
  float wd = w[og*2*C + c];
  float wx = w[og*2*C + C + c];
  wcat[o*C + c] = wd;
  wcat[(Osub+o)*C + c] = wx - wd;
}

// ---------- gather-max epilogue of edgeconv ----------
__global__ void gathermax_kernel(const float* __restrict__ tb, const int* __restrict__ idx,
                                 const float* __restrict__ sv, const float* __restrict__ bv,
                                 int O, float* __restrict__ out, int ldo)
{
  int t = blockIdx.x*256 + threadIdx.x;
  int o = t % O;
  int m = t / O;           // b*N + i
  int b = m / Nn;
  const int twoO = 2*O;
  const int* ip = idx + (size_t)m*Kk;
  float mx = -1e30f;
  for (int j = 0; j < Kk; ++j){
    int jj = ip[j] & (Nn-1);
    mx = fmaxf(mx, tb[(size_t)(b*Nn + jj)*twoO + o]);
  }
  float basev = tb[(size_t)m*twoO + O + o];
  float y = (mx + basev) * sv[o] + bv[o];
  out[(size_t)m*ldo + o] = lrelu_f(y);
}

// ---------- ordered-uint float max keys ----------
__device__ __forceinline__ unsigned fkey(float f){
  unsigned u = __float_as_uint(f);
  return (u & 0x80000000u) ? ~u : (u | 0x80000000u);
}
__device__ __forceinline__ float funkey(unsigned k){
  if (k == 0u) return -1e30f;
  unsigned u = (k & 0x80000000u) ? (k ^ 0x80000000u) : ~k;
  return __uint_as_float(u);
}

// ---------- generic fp32 GEMM: C[M,O] = A[M,K] @ W[O,K]^T (+epilogue / pool) ----------
__global__ __launch_bounds__(256) void gemm_kernel(
    const float* __restrict__ A, int lda,
    const float* __restrict__ W, int ldw,
    float* __restrict__ Cf, int ldc,
    int K, int O,
    const float* __restrict__ scale, const float* __restrict__ bias,
    const float* __restrict__ addvec, int lrelu_flag,
    unsigned* __restrict__ pool)
{
  const int tid = threadIdx.x;
  const int tx = tid & 15, ty = tid >> 4;
  const int m0 = blockIdx.y * 64;
  const int o0 = blockIdx.x * 64;
  __shared__ __align__(16) float As[16*68];
  __shared__ __align__(16) float Ws[16*68];
  float acc[4][4] = {};
  for (int k0 = 0; k0 < K; k0 += 16){
    __syncthreads();
    #pragma unroll
    for (int r = 0; r < 4; ++r){
      int e = tid + r*256;
      int k = e & 15, mi = e >> 4;
      int kk = k0 + k;
      float v = 0.f, wv = 0.f;
      if (kk < K) v = A[(size_t)(m0+mi)*lda + kk];
      int oo = o0 + mi;
      if (kk < K && oo < O) wv = W[(size_t)oo*ldw + kk];
      As[k*68 + mi] = v;
      Ws[k*68 + mi] = wv;
    }
    __syncthreads();
    #pragma unroll
    for (int kk = 0; kk < 16; ++kk){
      float4 av = *reinterpret_cast<const float4*>(&As[kk*68 + ty*4]);
      float4 wv = *reinterpret_cast<const float4*>(&Ws[kk*68 + tx*4]);
      float a4[4] = {av.x, av.y, av.z, av.w};
      float w4[4] = {wv.x, wv.y, wv.z, wv.w};
      #pragma unroll
      for (int i = 0; i < 4; ++i)
        #pragma unroll
        for (int j = 0; j < 4; ++j)
          acc[i][j] += a4[i]*w4[j];
    }
  }
  const int b = m0 / Nn;
  if (pool){
    float cm[4];
    #pragma unroll
    for (int j = 0; j < 4; ++j){
      int o = o0 + tx*4 + j;
      float m = -1e30f;
      #pragma unroll
      for (int i = 0; i < 4; ++i){
        float y = acc[i][j];
        if (addvec) y += addvec[b*O + o];
        y = y*scale[o] + bias[o];
        y = lrelu_f(y);
        m = fmaxf(m, y);
      }
      cm[j] = m;
    }
    __syncthreads();
    #pragma unroll
    for (int j = 0; j < 4; ++j) As[ty*68 + tx*4 + j] = cm[j];
    __syncthreads();
    if (tid < 64){
      float m = -1e30f;
      #pragma unroll
      for (int r = 0; r < 16; ++r) m = fmaxf(m, As[r*68 + tid]);
      atomicMax(&pool[b*O + o0 + tid], fkey(m));
    }
    return;
  }
  #pragma unroll
  for (int i = 0; i < 4; ++i){
    int m = m0 + ty*4 + i;
    #pragma unroll
    for (int j = 0; j < 4; ++j){
      int o = o0 + tx*4 + j;
      if (o >= O) continue;
      float y = acc[i][j];
      if (addvec) y += addvec[b*O + o];
      if (scale)  y = y*scale[o] + bias[o];
      else if (bias) y += bias[o];
      if (lrelu_flag) y = lrelu_f(y);
      Cf[(size_t)m*ldc + o] = y;
    }
  }
}

__global__ void init_u32_kernel(unsigned* __restrict__ p, int n){
  int t = blockIdx.x*256 + threadIdx.x;
  if (t < n) p[t] = 0u;
}
// gvec[b,o2] = sum_c wh1[o2, 512+c] * glob[b,c]  (one wave per (b,o2))
__global__ void gvec_kernel(const float* __restrict__ wh1, int ldw, const unsigned* __restrict__ glob,
                            int Oe, float* __restrict__ gv){
  int lane = threadIdx.x & 63, w = threadIdx.x >> 6;
  int o2 = blockIdx.x*4 + w;
  int b = blockIdx.y;
  const float* wr = wh1 + (size_t)o2*ldw + 512;
  float s = 0.f;
  for (int c = lane; c < Oe; c += 64) s += wr[c] * funkey(glob[b*Oe + c]);
  #pragma unroll
  for (int off = 32; off >= 1; off >>= 1) s += __shfl_xor(s, off, 64);
  if (lane == 0) gv[b*256 + o2] = s;
}

extern "C" void kernel_launch(void* const* d_in, const int* in_sizes, int n_in,
                              void* d_out, int out_size, void* d_ws, size_t ws_size,
                              hipStream_t stream) {
  (void)in_sizes; (void)n_in; (void)out_size; (void)ws_size;

  float* ws = (float*)d_ws;
  size_t off = 0;
  auto alloc = [&](size_t n){ float* p = ws + off; off += n; return p; };
  int*   dflag = (int*)alloc(16);
  float* xyzf = alloc((size_t)Mm*3);
  float* w1f  = alloc(64*6);
  float* w2f  = alloc(64*128);
  float* w3f  = alloc(128*256);
  float* w4f  = alloc(256*512);
  float* wff  = alloc(512*512);
  float* wef  = alloc(1024*512);
  float* wh1f = alloc(256*1536);
  float* wh2f = alloc(256*256);
  float* wh3f = alloc(50*256);
  float* wcat = alloc(512*128);
  float* nrm  = alloc(Mm);
  int*   idx  = (int*)alloc((size_t)Mm*Kk);
  unsigned* glob = (unsigned*)alloc(4096);
  float* gv   = alloc(1024);
  float* sfv = alloc(512);  float* bfv = alloc(512);
  float* sev = alloc(1024); float* bev = alloc(1024);
  float* sh1v = alloc(256); float* bh1v = alloc(256);
  float* sh2v = alloc(256); float* bh2v = alloc(256);
  float* bh3v = alloc(64);
  float* s1v = alloc(64);  float* b1v = alloc(64);
  float* s2v = alloc(64);  float* b2v = alloc(64);
  float* s3v = alloc(128); float* b3v = alloc(128);
  float* s4v = alloc(256); float* b4v = alloc(256);
  // big regions
  float* xcat = ws + 2000000;              // [M,512] fp32
  float* regC = ws + 10400000;             // 8.39M floats multipurpose
  float* dpart = regC;                               // [M][G<=8][20] floats
  int*   ipart = (int*)(regC + (size_t)Mm*8*20);     // [M][G<=8][20] ints
  float* tb    = regC;                     // [M, <=256] fp32 (after knn done)
  float* xloc  = regC;                     // [M,512] fp32
  float* logitsF = regC;                   // [M,50]
  float* h1 = xcat;                        // [M,256] (xcat dead after wf GEMM)
  float* h2 = xcat + (size_t)Mm*256;       // [M,256]

  // ---- dtype detect, then flag-gated conversions ----
  detect_kernel<<<1, 256, 0, stream>>>(d_in[0], Mm*3, dflag);
  auto cvt = [&](int i, float* dst, int n){
    load_input_kernel<<<(n+255)/256, 256, 0, stream>>>(d_in[i], dflag, dst, n);
  };
  cvt(0, xyzf, Mm*3);
  cvt(2, w1f, 64*6);    cvt(3, s1v, 64);   cvt(4, b1v, 64);
  cvt(5, w2f, 64*128);  cvt(6, s2v, 64);   cvt(7, b2v, 64);
  cvt(8, w3f, 128*256); cvt(9, s3v, 128);  cvt(10, b3v, 128);
  cvt(11, w4f, 256*512);cvt(12, s4v, 256); cvt(13, b4v, 256);
  cvt(14, wff, 512*512);  cvt(15, sfv, 512);  cvt(16, bfv, 512);
  cvt(17, wef, 1024*512); cvt(18, sev, 1024); cvt(19, bev, 1024);
  cvt(20, wh1f, 256*1536);cvt(21, sh1v, 256); cvt(22, bh1v, 256);
  cvt(23, wh2f, 256*256); cvt(24, sh2v, 256); cvt(25, bh2v, 256);
  cvt(26, wh3f, 50*256);  cvt(27, bh3v, 50);
  init_u32_kernel<<<16, 256, 0, stream>>>(glob, 4096);

  auto gemm = [&](const float* A, int lda, const float* W, int ldw,
                  float* Cf, int ldc, int K, int O,
                  const float* sc, const float* bi, const float* av, int lr,
                  unsigned* pool){
    dim3 g((O+63)/64, Mm/64);
    gemm_kernel<<<g, 256, 0, stream>>>(A, lda, W, ldw, Cf, ldc, K, O, sc, bi, av, lr, pool);
  };

  auto edgeconv = [&](const float* xin, int ld, int C, int O,
                      const float* w, const float* sv, const float* bv,
                      float* xout, int ldo){
    norms_kernel<<<Mm/256, 256, 0, stream>>>(xin, ld, C, Mm, nrm);
    int G;
    if (C == 3){
      G = 8;
      knn3_kernel<<<dim3(Nn/256, 8, Bb), 256, 0, stream>>>(xin, nrm, dpart, ipart);
    } else if (C == 64){
      G = 4;
      knn_split_kernel<64,4><<<dim3(Nn/64, 4, Bb), 256, 0, stream>>>(xin, ld, nrm, dpart, ipart);
    } else {
      G = 4;
      knn_split_kernel<128,4><<<dim3(Nn/64, 4, Bb), 256, 0, stream>>>(xin, ld, nrm, dpart, ipart);
    }
    knn_final_merge_kernel<<<Mm/256, 256, 0, stream>>>(dpart, ipart, G, idx);
    int chunk = (O > 128) ? 128 : O;
    for (int o0 = 0; o0 < O; o0 += chunk){
      int Osub = chunk;
      prep_w_kernel<<<(Osub*C+255)/256, 256, 0, stream>>>(w, C, o0, Osub, wcat);
      gemm(xin, ld, wcat, C, tb, 2*Osub, C, 2*Osub, nullptr, nullptr, nullptr, 0, nullptr);
      gathermax_kernel<<<((size_t)Mm*Osub)/256, 256, 0, stream>>>(
          tb, idx, sv + o0, bv + o0, Osub, xout + o0, ldo);
    }
  };

  edgeconv(xyzf, 3, 3, 64,            w1f, s1v, b1v, xcat + 0,   512);
  edgeconv(xcat + 0,   512, 64, 64,   w2f, s2v, b2v, xcat + 64,  512);
  edgeconv(xcat + 64,  512, 64, 128,  w3f, s3v, b3v, xcat + 128, 512);
  edgeconv(xcat + 128, 512, 128, 256, w4f, s4v, b4v, xcat + 256, 512);

  // x_local = lrelu((x_cat @ wf^T)*sf + bf)
  gemm(xcat, 512, wff, 512, xloc, 512, 512, 512, sfv, bfv, nullptr, 1, nullptr);
  // x_emb GEMM fused with global max pool -> glob
  gemm(xloc, 512, wef, 512, nullptr, 0, 512, 1024, sev, bev, nullptr, 1, glob);
  gvec_kernel<<<dim3(64, Bb), 256, 0, stream>>>(wh1f, 1536, glob, 1024, gv);
  // h1 = lrelu((x_local @ wh1[:, :512]^T + gvec)*sh1 + bh1)
  gemm(xloc, 512, wh1f, 1536, h1, 256, 512, 256, sh1v, bh1v, gv, 1, nullptr);
  // h2
  gemm(h1, 256, wh2f, 256, h2, 256, 256, 256, sh2v, bh2v, nullptr, 1, nullptr);
  // logits (fp32 scratch), then flag-gated store to d_out
  gemm(h2, 256, wh3f, 256, logitsF, 50, 256, 50, nullptr, bh3v, nullptr, 0, nullptr);
  store_out_kernel<<<((size_t)Mm*50 + 255)/256, 256, 0, stream>>>(logitsF, dflag, d_out, Mm*50);
}

// Round 7
// 2921.360 us; speedup vs baseline: 1.6500x; 1.1097x over previous
//
#include <hip/hip_runtime.h>
#include <hip/hip_bf16.h>
#include <cstdint>

#define LEAKV 0.2f
static const int Bb = 4, Nn = 4096, Mm = 16384, Kk = 20;

typedef __attribute__((ext_vector_type(8))) short bf16x8;
typedef __attribute__((ext_vector_type(4))) float f32x4;

__device__ __forceinline__ float lrelu_f(float v){ return v > 0.f ? v : LEAKV*v; }

// ---------- dtype detector: read as bf16, count wild values ----------
__global__ void detect_kernel(const void* __restrict__ xyz, int n, int* __restrict__ flag){
  __shared__ int cnt;
  if (threadIdx.x == 0) cnt = 0;
  __syncthreads();
  const __hip_bfloat16* p = (const __hip_bfloat16*)xyz;
  int local = 0;
  for (int i = threadIdx.x; i < n; i += 256){
    float v = __bfloat162float(p[i]);
    if (!(fabsf(v) < 1000.f)) local++;
  }
  atomicAdd(&cnt, local);
  __syncthreads();
  if (threadIdx.x == 0) *flag = (cnt < n/16) ? 1 : 0;   // 1 = bf16, 0 = fp32
}

// ---------- flag-gated input load -> fp32 ----------
__global__ void load_input_kernel(const void* __restrict__ src, const int* __restrict__ flag,
                                  float* __restrict__ out, int n){
  int t = blockIdx.x*256 + threadIdx.x;
  if (t >= n) return;
  if (*flag) out[t] = __bfloat162float(((const __hip_bfloat16*)src)[t]);
  else       out[t] = ((const float*)src)[t];
}

// ---------- flag-gated output store ----------
__global__ void store_out_kernel(const float* __restrict__ src, const int* __restrict__ flag,
                                 void* __restrict__ dst, int n){
  int t = blockIdx.x*256 + threadIdx.x;
  if (t >= n) return;
  float v = src[t];
  if (*flag) ((__hip_bfloat16*)dst)[t] = __float2bfloat16(v);
  else       ((float*)dst)[t] = v;
}

// ---------- squared norms ----------
__global__ void norms_kernel(const float* __restrict__ x, int ld, int C, int total, float* __restrict__ out){
  int t = blockIdx.x*256 + threadIdx.x;
  if (t >= total) return;
  const float* r = x + (size_t)t*ld;
  float s = 0.f;
  for (int c = 0; c < C; ++c){ float v = r[c]; s += v*v; }
  out[t] = s;
}

// ---------- split fp32 -> bf16 hi + bf16 lo (packed [M,C]) ----------
__global__ void prep_hl_kernel(const float* __restrict__ x, int ld, int C,
                               __hip_bfloat16* __restrict__ Xh, __hip_bfloat16* __restrict__ Xl){
  int t = blockIdx.x*256 + threadIdx.x;
  if (t >= Mm*C) return;
  int m = t / C, c = t - m*C;
  float v = x[(size_t)m*ld + c];
  __hip_bfloat16 h = __float2bfloat16(v);
  float r = v - __bfloat162float(h);     // exact (Sterbenz)
  Xh[t] = h;
  Xl[t] = __float2bfloat16(r);
}

// ---------- MFMA KNN: wave owns 16 queries; 3-pass bf16 hi/lo distances ----------
template<int C, int G>
__global__ __launch_bounds__(256, 3) void knn_mfma_kernel(
    const __hip_bfloat16* __restrict__ Xh, const __hip_bfloat16* __restrict__ Xl,
    const float* __restrict__ n2,
    float* __restrict__ outd, int* __restrict__ outi)
{
  constexpr int KS = C/32;
  __shared__ float Dt[4][16*17];
  const int tid = threadIdx.x;
  const int lane = tid & 63;
  const int w = tid >> 6;
  const int b = blockIdx.z, bN = b*Nn;
  const int q0 = blockIdx.x*64 + w*16;
  const int g = blockIdx.y;
  const int kq = (lane >> 4) * 8;

  // persistent query fragments (A-operand layout: row=lane&15, k=quad*8+j)
  bf16x8 Ah[KS], Al[KS];
  {
    const size_t qrow = (size_t)(bN + q0 + (lane & 15))*C;
    #pragma unroll
    for (int s = 0; s < KS; ++s){
      Ah[s] = *reinterpret_cast<const bf16x8*>(Xh + qrow + s*32 + kq);
      Al[s] = *reinterpret_cast<const bf16x8*>(Xl + qrow + s*32 + kq);
    }
  }

  float bd[20]; int bi[20];
  #pragma unroll
  for (int l = 0; l < 20; ++l){ bd[l] = 1e30f; bi[l] = 0x7fffffff; }
  float worst = 1e30f; int wp = 0;

  const int NT = (Nn/G)/16;
  float* dtw = Dt[w];
  for (int jt = 0; jt < NT; ++jt){
    const int j0 = g*(Nn/G) + jt*16;
    const size_t crow = (size_t)(bN + j0 + (lane & 15))*C;
    f32x4 acc = {0.f, 0.f, 0.f, 0.f};
    #pragma unroll
    for (int s = 0; s < KS; ++s){
      bf16x8 Bh = *reinterpret_cast<const bf16x8*>(Xh + crow + s*32 + kq);
      bf16x8 Bl = *reinterpret_cast<const bf16x8*>(Xl + crow + s*32 + kq);
      acc = __builtin_amdgcn_mfma_f32_16x16x32_bf16(Ah[s], Bh, acc, 0, 0, 0);
      acc = __builtin_amdgcn_mfma_f32_16x16x32_bf16(Ah[s], Bl, acc, 0, 0, 0);
      acc = __builtin_amdgcn_mfma_f32_16x16x32_bf16(Al[s], Bh, acc, 0, 0, 0);
    }
    // C/D layout: col=lane&15 (cand), row=(lane>>4)*4+r (query)
    float nj = n2[bN + j0 + (lane & 15)];
    const int rbase = (lane >> 4)*4;
    #pragma unroll
    for (int r = 0; r < 4; ++r)
      dtw[(rbase + r)*17 + (lane & 15)] = nj - 2.f*acc[r];
    // intra-wave LDS exchange (wave64 lockstep; per-wave DS ops are ordered)
    const float* rowp = dtw + (lane >> 2)*17 + (lane & 3)*4;
    #pragma unroll
    for (int t = 0; t < 4; ++t){
      float d = rowp[t];
      if (d < worst){
        int j = j0 + (lane & 3)*4 + t;
        #pragma unroll
        for (int l = 0; l < 20; ++l) if (l == wp){ bd[l] = d; bi[l] = j; }
        worst = bd[0]; wp = 0;
        #pragma unroll
        for (int l = 1; l < 20; ++l) if (bd[l] > worst){ worst = bd[l]; wp = l; }
      }
    }
  }

  // merge each query's 4 partial lists (lanes 4q..4q+3) via shfl; leader = lane%4==0
  float wd_ = bd[0]; int wi_ = bi[0]; int wp_ = 0;
  #pragma unroll
  for (int l = 1; l < 20; ++l)
    if (bd[l] > wd_ || (bd[l] == wd_ && bi[l] > wi_)){ wd_ = bd[l]; wi_ = bi[l]; wp_ = l; }
  const bool leader = (lane & 3) == 0;
  for (int p = 1; p < 4; ++p){
    #pragma unroll
    for (int l = 0; l < 20; ++l){
      float od = __shfl(bd[l], (lane & 60) + p, 64);
      int   oi = __shfl(bi[l], (lane & 60) + p, 64);
      bool better = leader && ((od < wd_) || (od == wd_ && oi < wi_));
      if (better){
        #pragma unroll
        for (int l2 = 0; l2 < 20; ++l2) if (l2 == wp_){ bd[l2] = od; bi[l2] = oi; }
        wd_ = bd[0]; wi_ = bi[0]; wp_ = 0;
        #pragma unroll
        for (int l2 = 1; l2 < 20; ++l2)
          if (bd[l2] > wd_ || (bd[l2] == wd_ && bi[l2] > wi_)){ wd_ = bd[l2]; wi_ = bi[l2]; wp_ = l2; }
      }
    }
  }
  if (leader){
    const int q = q0 + (lane >> 2);
    size_t base = ((size_t)(bN + q)*G + g)*20;
    #pragma unroll
    for (int l = 0; l < 20; ++l){ outd[base + l] = bd[l]; outi[base + l] = bi[l]; }
  }
}

// ---------- KNN for C=3: 1 thread/query, candidates broadcast from LDS, G=8 ----------
__global__ __launch_bounds__(256, 4) void knn3_kernel(
    const float* __restrict__ x, const float* __restrict__ n2,
    float* __restrict__ outd, int* __restrict__ outi)
{
  __shared__ __align__(16) float cs[512*4];
  const int tid = threadIdx.x;
  const int b = blockIdx.z, bN = b*Nn;
  const int g = blockIdx.y;                 // 0..7
  const int q = blockIdx.x*256 + tid;
  float qx = x[(size_t)(bN+q)*3 + 0];
  float qy = x[(size_t)(bN+q)*3 + 1];
  float qz = x[(size_t)(bN+q)*3 + 2];
  for (int e = tid; e < 512; e += 256){
    int j = g*512 + e;
    cs[e*4+0] = x[(size_t)(bN+j)*3 + 0];
    cs[e*4+1] = x[(size_t)(bN+j)*3 + 1];
    cs[e*4+2] = x[(size_t)(bN+j)*3 + 2];
    cs[e*4+3] = n2[bN+j];
  }
  __syncthreads();
  float bd[20]; int bi[20];
  #pragma unroll
  for (int l = 0; l < 20; ++l){ bd[l] = 1e30f; bi[l] = 0x7fffffff; }
  float worst = 1e30f; int wp = 0;
  for (int t = 0; t < 512; ++t){
    float4 c = *reinterpret_cast<const float4*>(&cs[t*4]);
    float d = c.w - 2.f*(qx*c.x + qy*c.y + qz*c.z);
    if (d < worst){
      int j = g*512 + t;
      #pragma unroll
      for (int l = 0; l < 20; ++l) if (l == wp){ bd[l] = d; bi[l] = j; }
      worst = bd[0]; wp = 0;
      #pragma unroll
      for (int l = 1; l < 20; ++l) if (bd[l] > worst){ worst = bd[l]; wp = l; }
    }
  }
  size_t base = ((size_t)(bN + q)*8 + g)*20;
  #pragma unroll
  for (int l = 0; l < 20; ++l){ outd[base + l] = bd[l]; outi[base + l] = bi[l]; }
}

// ---------- final merge: G lists of 20 -> top-20 (register resident) ----------
__global__ __launch_bounds__(256, 4) void knn_final_merge_kernel(
    const float* __restrict__ ind, const int* __restrict__ ini, int G,
    int* __restrict__ idx)
{
  int t = blockIdx.x*256 + threadIdx.x;
  if (t >= Mm) return;
  size_t base = (size_t)t*G*20;
  float fd[20]; int fi[20];
  #pragma unroll
  for (int l = 0; l < 20; ++l){ fd[l] = 1e30f; fi[l] = 0x7fffffff; }
  float wd_ = 1e30f; int wi_ = 0x7fffffff; int wp_ = 0;
  for (int e = 0; e < G*20; ++e){
    float d = ind[base + e];
    int   id = ini[base + e];
    bool better = (d < wd_) || (d == wd_ && id < wi_);
    if (better){
      #pragma unroll
      for (int l = 0; l < 20; ++l) if (l == wp_){ fd[l] = d; fi[l] = id; }
      wd_ = fd[0]; wi_ = fi[0]; wp_ = 0;
      #pragma unroll
      for (int l = 1; l < 20; ++l)
        if (fd[l] > wd_ || (fd[l] == wd_ && fi[l] > wi_)){ wd_ = fd[l]; wi_ = fi[l]; wp_ = l; }
    }
  }
  #pragma unroll
  for (int l = 0; l < 20; ++l) idx[(size_t)t*Kk + l] = fi[l];
}

// ---------- prepare edgeconv weights (fp32 in): wcat = [w_d ; w_x - w_d] ----------
__global__ void prep_w_kernel(const float* __restrict__ w, int C, int o0, int Osub,
                              float* __restrict__ wcat){
  int t = blockIdx.x*256 + threadIdx.x;
  if (t >= Osub*C) return;
  int o = t / C, c = t - o*C;
  int og = o0 + o;
  float wd = w[og*2*C + c];
  float wx = w[og*2*C + C + c];
  wcat[o*C + c] = wd;
  wcat[(Osub+o)*C + c] = wx - wd;
}

// ---------- gather-max epilogue of edgeconv ----------
__global__ void gathermax_kernel(const float* __restrict__ tb, const int* __restrict__ idx,
                                 const float* __restrict__ sv, const float* __restrict__ bv,
                                 int O, float* __restrict__ out, int ldo)
{
  int t = blockIdx.x*256 + threadIdx.x;
  int o = t % O;
  int m = t / O;           // b*N + i
  int b = m / Nn;
  const int twoO = 2*O;
  const int* ip = idx + (size_t)m*Kk;
  float mx = -1e30f;
  for (int j = 0; j < Kk; ++j){
    int jj = ip[j] & (Nn-1);
    mx = fmaxf(mx, tb[(size_t)(b*Nn + jj)*twoO + o]);
  }
  float basev = tb[(size_t)m*twoO + O + o];
  float y = (mx + basev) * sv[o] + bv[o];
  out[(size_t)m*ldo + o] = lrelu_f(y);
}

// ---------- ordered-uint float max keys ----------
__device__ __forceinline__ unsigned fkey(float f){
  unsigned u = __float_as_uint(f);
  return (u & 0x80000000u) ? ~u : (u | 0x80000000u);
}
__device__ __forceinline__ float funkey(unsigned k){
  if (k == 0u) return -1e30f;
  unsigned u = (k & 0x80000000u) ? (k ^ 0x80000000u) : ~k;
  return __uint_as_float(u);
}

// ---------- generic fp32 GEMM: C[M,O] = A[M,K] @ W[O,K]^T (+epilogue / pool) ----------
__global__ __launch_bounds__(256) void gemm_kernel(
    const float* __restrict__ A, int lda,
    const float* __restrict__ W, int ldw,
    float* __restrict__ Cf, int ldc,
    int K, int O,
    const float* __restrict__ scale, const float* __restrict__ bias,
    const float* __restrict__ addvec, int lrelu_flag,
    unsigned* __restrict__ pool)
{
  const int tid = threadIdx.x;
  const int tx = tid & 15, ty = tid >> 4;
  const int m0 = blockIdx.y * 64;
  const int o0 = blockIdx.x * 64;
  __shared__ __align__(16) float As[16*68];
  __shared__ __align__(16) float Ws[16*68];
  float acc[4][4] = {};
  for (int k0 = 0; k0 < K; k0 += 16){
    __syncthreads();
    #pragma unroll
    for (int r = 0; r < 4; ++r){
      int e = tid + r*256;
      int k = e & 15, mi = e >> 4;
      int kk = k0 + k;
      float v = 0.f, wv = 0.f;
      if (kk < K) v = A[(size_t)(m0+mi)*lda + kk];
      int oo = o0 + mi;
      if (kk < K && oo < O) wv = W[(size_t)oo*ldw + kk];
      As[k*68 + mi] = v;
      Ws[k*68 + mi] = wv;
    }
    __syncthreads();
    #pragma unroll
    for (int kk = 0; kk < 16; ++kk){
      float4 av = *reinterpret_cast<const float4*>(&As[kk*68 + ty*4]);
      float4 wv = *reinterpret_cast<const float4*>(&Ws[kk*68 + tx*4]);
      float a4[4] = {av.x, av.y, av.z, av.w};
      float w4[4] = {wv.x, wv.y, wv.z, wv.w};
      #pragma unroll
      for (int i = 0; i < 4; ++i)
        #pragma unroll
        for (int j = 0; j < 4; ++j)
          acc[i][j] += a4[i]*w4[j];
    }
  }
  const int b = m0 / Nn;
  if (pool){
    float cm[4];
    #pragma unroll
    for (int j = 0; j < 4; ++j){
      int o = o0 + tx*4 + j;
      float m = -1e30f;
      #pragma unroll
      for (int i = 0; i < 4; ++i){
        float y = acc[i][j];
        if (addvec) y += addvec[b*O + o];
        y = y*scale[o] + bias[o];
        y = lrelu_f(y);
        m = fmaxf(m, y);
      }
      cm[j] = m;
    }
    __syncthreads();
    #pragma unroll
    for (int j = 0; j < 4; ++j) As[ty*68 + tx*4 + j] = cm[j];
    __syncthreads();
    if (tid < 64){
      float m = -1e30f;
      #pragma unroll
      for (int r = 0; r < 16; ++r) m = fmaxf(m, As[r*68 + tid]);
      atomicMax(&pool[b*O + o0 + tid], fkey(m));
    }
    return;
  }
  #pragma unroll
  for (int i = 0; i < 4; ++i){
    int m = m0 + ty*4 + i;
    #pragma unroll
    for (int j = 0; j < 4; ++j){
      int o = o0 + tx*4 + j;
      if (o >= O) continue;
      float y = acc[i][j];
      if (addvec) y += addvec[b*O + o];
      if (scale)  y = y*scale[o] + bias[o];
      else if (bias) y += bias[o];
      if (lrelu_flag) y = lrelu_f(y);
      Cf[(size_t)m*ldc + o] = y;
    }
  }
}

__global__ void init_u32_kernel(unsigned* __restrict__ p, int n){
  int t = blockIdx.x*256 + threadIdx.x;
  if (t < n) p[t] = 0u;
}
// gvec[b,o2] = sum_c wh1[o2, 512+c] * glob[b,c]  (one wave per (b,o2))
__global__ void gvec_kernel(const float* __restrict__ wh1, int ldw, const unsigned* __restrict__ glob,
                            int Oe, float* __restrict__ gv){
  int lane = threadIdx.x & 63, w = threadIdx.x >> 6;
  int o2 = blockIdx.x*4 + w;
  int b = blockIdx.y;
  const float* wr = wh1 + (size_t)o2*ldw + 512;
  float s = 0.f;
  for (int c = lane; c < Oe; c += 64) s += wr[c] * funkey(glob[b*Oe + c]);
  #pragma unroll
  for (int off = 32; off >= 1; off >>= 1) s += __shfl_xor(s, off, 64);
  if (lane == 0) gv[b*256 + o2] = s;
}

extern "C" void kernel_launch(void* const* d_in, const int* in_sizes, int n_in,
                              void* d_out, int out_size, void* d_ws, size_t ws_size,
                              hipStream_t stream) {
  (void)in_sizes; (void)n_in; (void)out_size; (void)ws_size;

  float* ws = (float*)d_ws;
  size_t off = 0;
  auto alloc = [&](size_t n){ float* p = ws + off; off += n; return p; };
  int*   dflag = (int*)alloc(16);
  float* xyzf = alloc((size_t)Mm*3);
  float* w1f  = alloc(64*6);
  float* w2f  = alloc(64*128);
  float* w3f  = alloc(128*256);
  float* w4f  = alloc(256*512);
  float* wff  = alloc(512*512);
  float* wef  = alloc(1024*512);
  float* wh1f = alloc(256*1536);
  float* wh2f = alloc(256*256);
  float* wh3f = alloc(50*256);
  float* wcat = alloc(512*128);
  float* nrm  = alloc(Mm);
  int*   idx  = (int*)alloc((size_t)Mm*Kk);
  unsigned* glob = (unsigned*)alloc(4096);
  float* gv   = alloc(1024);
  float* sfv = alloc(512);  float* bfv = alloc(512);
  float* sev = alloc(1024); float* bev = alloc(1024);
  float* sh1v = alloc(256); float* bh1v = alloc(256);
  float* sh2v = alloc(256); float* bh2v = alloc(256);
  float* bh3v = alloc(64);
  float* s1v = alloc(64);  float* b1v = alloc(64);
  float* s2v = alloc(64);  float* b2v = alloc(64);
  float* s3v = alloc(128); float* b3v = alloc(128);
  float* s4v = alloc(256); float* b4v = alloc(256);
  // big regions
  float* xcat = ws + 2000000;              // [M,512] fp32
  float* regC = ws + 10400000;             // 8.39M floats multipurpose
  float* dpart = regC;                               // [M][G<=8][20] floats
  int*   ipart = (int*)(regC + (size_t)Mm*8*20);     // [M][G<=8][20] ints
  __hip_bfloat16* Xh = (__hip_bfloat16*)(regC + 5300000);   // [M,128] bf16 hi
  __hip_bfloat16* Xl = Xh + (size_t)Mm*128;                 // [M,128] bf16 lo
  float* tb    = regC;                     // [M, <=256] fp32 (after knn done)
  float* xloc  = regC;                     // [M,512] fp32
  float* logitsF = regC;                   // [M,50]
  float* h1 = xcat;                        // [M,256] (xcat dead after wf GEMM)
  float* h2 = xcat + (size_t)Mm*256;       // [M,256]

  // ---- dtype detect, then flag-gated conversions ----
  detect_kernel<<<1, 256, 0, stream>>>(d_in[0], Mm*3, dflag);
  auto cvt = [&](int i, float* dst, int n){
    load_input_kernel<<<(n+255)/256, 256, 0, stream>>>(d_in[i], dflag, dst, n);
  };
  cvt(0, xyzf, Mm*3);
  cvt(2, w1f, 64*6);    cvt(3, s1v, 64);   cvt(4, b1v, 64);
  cvt(5, w2f, 64*128);  cvt(6, s2v, 64);   cvt(7, b2v, 64);
  cvt(8, w3f, 128*256); cvt(9, s3v, 128);  cvt(10, b3v, 128);
  cvt(11, w4f, 256*512);cvt(12, s4v, 256); cvt(13, b4v, 256);
  cvt(14, wff, 512*512);  cvt(15, sfv, 512);  cvt(16, bfv, 512);
  cvt(17, wef, 1024*512); cvt(18, sev, 1024); cvt(19, bev, 1024);
  cvt(20, wh1f, 256*1536);cvt(21, sh1v, 256); cvt(22, bh1v, 256);
  cvt(23, wh2f, 256*256); cvt(24, sh2v, 256); cvt(25, bh2v, 256);
  cvt(26, wh3f, 50*256);  cvt(27, bh3v, 50);
  init_u32_kernel<<<16, 256, 0, stream>>>(glob, 4096);

  auto gemm = [&](const float* A, int lda, const float* W, int ldw,
                  float* Cf, int ldc, int K, int O,
                  const float* sc, const float* bi, const float* av, int lr,
                  unsigned* pool){
    dim3 g((O+63)/64, Mm/64);
    gemm_kernel<<<g, 256, 0, stream>>>(A, lda, W, ldw, Cf, ldc, K, O, sc, bi, av, lr, pool);
  };

  auto edgeconv = [&](const float* xin, int ld, int C, int O,
                      const float* w, const float* sv, const float* bv,
                      float* xout, int ldo){
    norms_kernel<<<Mm/256, 256, 0, stream>>>(xin, ld, C, Mm, nrm);
    int G;
    if (C == 3){
      G = 8;
      knn3_kernel<<<dim3(Nn/256, 8, Bb), 256, 0, stream>>>(xin, nrm, dpart, ipart);
    } else {
      G = 4;
      prep_hl_kernel<<<(Mm*C+255)/256, 256, 0, stream>>>(xin, ld, C, Xh, Xl);
      if (C == 64)
        knn_mfma_kernel<64,4><<<dim3(Nn/64, 4, Bb), 256, 0, stream>>>(Xh, Xl, nrm, dpart, ipart);
      else
        knn_mfma_kernel<128,4><<<dim3(Nn/64, 4, Bb), 256, 0, stream>>>(Xh, Xl, nrm, dpart, ipart);
    }
    knn_final_merge_kernel<<<Mm/256, 256, 0, stream>>>(dpart, ipart, G, idx);
    int chunk = (O > 128) ? 128 : O;
    for (int o0 = 0; o0 < O; o0 += chunk){
      int Osub = chunk;
      prep_w_kernel<<<(Osub*C+255)/256, 256, 0, stream>>>(w, C, o0, Osub, wcat);
      gemm(xin, ld, wcat, C, tb, 2*Osub, C, 2*Osub, nullptr, nullptr, nullptr, 0, nullptr);
      gathermax_kernel<<<((size_t)Mm*Osub)/256, 256, 0, stream>>>(
          tb, idx, sv + o0, bv + o0, Osub, xout + o0, ldo);
    }
  };

  edgeconv(xyzf, 3, 3, 64,            w1f, s1v, b1v, xcat + 0,   512);
  edgeconv(xcat + 0,   512, 64, 64,   w2f, s2v, b2v, xcat + 64,  512);
  edgeconv(xcat + 64,  512, 64, 128,  w3f, s3v, b3v, xcat + 128, 512);
  edgeconv(xcat + 128, 512, 128, 256, w4f, s4v, b4v, xcat + 256, 512);

  // x_local = lrelu((x_cat @ wf^T)*sf + bf)
  gemm(xcat, 512, wff, 512, xloc, 512, 512, 512, sfv, bfv, nullptr, 1, nullptr);
  // x_emb GEMM fused with global max pool -> glob
  gemm(xloc, 512, wef, 512, nullptr, 0, 512, 1024, sev, bev, nullptr, 1, glob);
  gvec_kernel<<<dim3(64, Bb), 256, 0, stream>>>(wh1f, 1536, glob, 1024, gv);
  // h1 = lrelu((x_local @ wh1[:, :512]^T + gvec)*sh1 + bh1)
  gemm(xloc, 512, wh1f, 1536, h1, 256, 512, 256, sh1v, bh1v, gv, 1, nullptr);
  // h2
  gemm(h1, 256, wh2f, 256, h2, 256, 256, 256, sh2v, bh2v, nullptr, 1, nullptr);
  // logits (fp32 scratch), then flag-gated store to d_out
  gemm(h2, 256, wh3f, 256, logitsF, 50, 256, 50, nullptr, bh3v, nullptr, 0, nullptr);
  store_out_kernel<<<((size_t)Mm*50 + 255)/256, 256, 0, stream>>>(logitsF, dflag, d_out, Mm*50);
}